// Round 7
// baseline (8831.408 us; speedup 1.0000x reference)
//
#include <hip/hip_runtime.h>

#define DIM 64
#define PART_BUCKETS 256      // buckets per partition
#define NPART_MAX 592         // >= (150016/256)=586
#define EPT 16                // edges per thread, pass1
#define EPB (EPT * 256)       // 4096 edges per block, pass1
#define CAP2 8192             // max records per partition for in-place sort

// ---------------- fallback (round-1) atomic kernel ----------------
__global__ void coo_scatter_kernel(const float* __restrict__ user_emb,
                                   const float* __restrict__ entity_emb,
                                   const int* __restrict__ rows,
                                   const int* __restrict__ cols,
                                   const float* __restrict__ vals,
                                   float* __restrict__ entity_agg,
                                   float* __restrict__ user_agg,
                                   int nnz) {
    long long tid = (long long)blockIdx.x * blockDim.x + threadIdx.x;
    long long total = (long long)nnz * DIM;
    if (tid >= total) return;
    int edge = (int)(tid >> 6);
    int d = (int)(tid & 63);
    int r = rows[edge];
    int c = cols[edge];
    float v = vals[edge];
    atomicAdd(&entity_agg[c * DIM + d], v * user_emb[r * DIM + d]);
    atomicAdd(&user_agg[r * DIM + d], v * entity_emb[c * DIM + d]);
}

// record: uint2 { meta, valbits }; meta = (local8<<18) | (side<<17) | src
// bucket = partition*256 + local8. side 0: gather user_emb; side 1: entity_emb.

// pass0: per-partition histogram (LDS-staged)
__global__ __launch_bounds__(256) void pass0_hist(const int* __restrict__ rows,
                                                  const int* __restrict__ cols,
                                                  int* __restrict__ pcnt,
                                                  int ne, int nnz, int npart) {
    __shared__ int h[NPART_MAX];
    for (int t = threadIdx.x; t < npart; t += 256) h[t] = 0;
    __syncthreads();
    for (int i = blockIdx.x * blockDim.x + threadIdx.x; i < nnz;
         i += gridDim.x * blockDim.x) {
        int c = cols[i];
        int r = rows[i];
        atomicAdd(&h[c >> 8], 1);
        atomicAdd(&h[(ne + r) >> 8], 1);
    }
    __syncthreads();
    for (int t = threadIdx.x; t < npart; t += 256)
        if (h[t]) atomicAdd(&pcnt[t], h[t]);
}

// scan over npart partition counts (single block, parallel)
__global__ __launch_bounds__(256) void scan_parts(const int* __restrict__ pcnt,
                                                  int* __restrict__ poffs,
                                                  int* __restrict__ pcursor,
                                                  int* __restrict__ ovfcnt,
                                                  int npart) {
    __shared__ int sh[256];
    int t = threadIdx.x;
    int local[3];
    int s = 0;
#pragma unroll
    for (int j = 0; j < 3; ++j) {
        int idx = t * 3 + j;
        local[j] = (idx < npart) ? pcnt[idx] : 0;
        s += local[j];
    }
    sh[t] = s;
    for (int off = 1; off < 256; off <<= 1) {
        __syncthreads();
        int tmp = (t >= off) ? sh[t - off] : 0;
        __syncthreads();
        sh[t] += tmp;
    }
    __syncthreads();
    int run = sh[t] - s;   // exclusive prefix
#pragma unroll
    for (int j = 0; j < 3; ++j) {
        int idx = t * 3 + j;
        if (idx < npart) {
            poffs[idx] = run;
            pcursor[idx] = run;
            run += local[j];
        }
    }
    if (t == 0) {
        poffs[npart] = sh[255];
        *ovfcnt = 0;
    }
}

// pass1: build records in registers, claim per-(block,partition) chunks,
// scatter. All writers of a chunk are one block -> single-L2 full lines.
__global__ __launch_bounds__(256) void pass1_part(const int* __restrict__ rows,
                                                  const int* __restrict__ cols,
                                                  const float* __restrict__ vals,
                                                  int* __restrict__ pcursor,
                                                  uint2* __restrict__ payload,
                                                  int ne, int nnz, int npart) {
    __shared__ int hist[NPART_MAX];
    __shared__ int cur[NPART_MAX];
    __shared__ int gbase[NPART_MAX];
    for (int t = threadIdx.x; t < npart; t += 256) { hist[t] = 0; cur[t] = 0; }
    __syncthreads();

    int base = blockIdx.x * EPB;
    uint2 rec[2 * EPT];
    int pid[2 * EPT];
#pragma unroll
    for (int k = 0; k < EPT; ++k) {
        int i = base + threadIdx.x + k * 256;
        if (i < nnz) {
            int r = rows[i];
            int c = cols[i];
            unsigned vb = __float_as_uint(vals[i]);
            int b2 = ne + r;
            int p1 = c >> 8;
            int p2 = b2 >> 8;
            rec[2 * k]     = make_uint2(((unsigned)(c & 255) << 18) | (unsigned)r, vb);
            rec[2 * k + 1] = make_uint2(((unsigned)(b2 & 255) << 18) | (1u << 17) | (unsigned)c, vb);
            pid[2 * k] = p1;
            pid[2 * k + 1] = p2;
            atomicAdd(&hist[p1], 1);
            atomicAdd(&hist[p2], 1);
        } else {
            pid[2 * k] = -1;
            pid[2 * k + 1] = -1;
        }
    }
    __syncthreads();
    for (int p = threadIdx.x; p < npart; p += 256) {
        int c_ = hist[p];
        if (c_) gbase[p] = atomicAdd(&pcursor[p], c_);
    }
    __syncthreads();
#pragma unroll
    for (int k = 0; k < 2 * EPT; ++k) {
        int p = pid[k];
        if (p >= 0) {
            int rank = atomicAdd(&cur[p], 1);
            payload[(size_t)gbase[p] + rank] = rec[k];
        }
    }
}

// pass2: one block per partition; in-place counting sort into 32 bins of
// 8 buckets; write per-bin [offs, ends).
__global__ __launch_bounds__(256) void pass2_sort(uint2* __restrict__ payload,
                                                  const int* __restrict__ poffs,
                                                  int* __restrict__ offs,
                                                  int* __restrict__ ends,
                                                  int* __restrict__ ovfcnt,
                                                  int* __restrict__ ovflist) {
    __shared__ int h[32], sc[32], cu[32];
    int p = blockIdx.x;
    int beg = poffs[p];
    int n = poffs[p + 1] - beg;
    int t = threadIdx.x;
    if (t < 32) h[t] = 0;
    __syncthreads();

    if (n > CAP2) {   // statistically never; handled by pass3 direct atomics
        if (t == 0) {
            int o = atomicAdd(ovfcnt, 1);
            ovflist[o] = p;
        }
        if (t < 32) { offs[p * 32 + t] = beg; ends[p * 32 + t] = beg; }
        return;
    }

    uint2 rec[32];
#pragma unroll
    for (int k = 0; k < 32; ++k) {
        int idx = t + k * 256;
        if (idx < n) {
            rec[k] = payload[(size_t)beg + idx];
            atomicAdd(&h[(rec[k].x >> 21) & 31], 1);
        }
    }
    __syncthreads();
    if (t == 0) {
        int run = 0;
#pragma unroll
        for (int j = 0; j < 32; ++j) { sc[j] = run; run += h[j]; }
    }
    __syncthreads();
    if (t < 32) {
        offs[p * 32 + t] = beg + sc[t];
        ends[p * 32 + t] = beg + sc[t] + h[t];
        cu[t] = sc[t];
    }
    __syncthreads();   // all reads done (records in regs) -> in-place write safe
#pragma unroll
    for (int k = 0; k < 32; ++k) {
        int idx = t + k * 256;
        if (idx < n) {
            int bin = (rec[k].x >> 21) & 31;
            int rank = atomicAdd(&cu[bin], 1);
            payload[(size_t)beg + rank] = rec[k];
        }
    }
}

// agg: one WAVE per bin (8 buckets); register accumulators; lane = dim.
__global__ __launch_bounds__(256) void agg_bins(const float* __restrict__ user_emb,
                                                const float* __restrict__ entity_emb,
                                                const int* __restrict__ offs,
                                                const int* __restrict__ ends,
                                                const uint2* __restrict__ payload,
                                                float* __restrict__ out,
                                                int nbins) {
    int wave = blockIdx.x * 4 + (threadIdx.x >> 6);
    int lane = threadIdx.x & 63;
    if (wave >= nbins) return;
    int beg = offs[wave];
    int end = ends[wave];

    float acc[8];
#pragma unroll
    for (int k = 0; k < 8; ++k) acc[k] = 0.f;

    int i = beg;
    for (; i + 4 <= end; i += 4) {
        uint2 r0 = payload[i + 0];
        uint2 r1 = payload[i + 1];
        uint2 r2 = payload[i + 2];
        uint2 r3 = payload[i + 3];
        const float* __restrict__ t0 = (r0.x & (1u << 17)) ? entity_emb : user_emb;
        const float* __restrict__ t1 = (r1.x & (1u << 17)) ? entity_emb : user_emb;
        const float* __restrict__ t2 = (r2.x & (1u << 17)) ? entity_emb : user_emb;
        const float* __restrict__ t3 = (r3.x & (1u << 17)) ? entity_emb : user_emb;
        float e0 = t0[(size_t)(r0.x & 0x1FFFFu) * DIM + lane];
        float e1 = t1[(size_t)(r1.x & 0x1FFFFu) * DIM + lane];
        float e2 = t2[(size_t)(r2.x & 0x1FFFFu) * DIM + lane];
        float e3 = t3[(size_t)(r3.x & 0x1FFFFu) * DIM + lane];
        float m0 = __uint_as_float(r0.y) * e0;
        float m1 = __uint_as_float(r1.y) * e1;
        float m2 = __uint_as_float(r2.y) * e2;
        float m3 = __uint_as_float(r3.y) * e3;
        unsigned l0 = (r0.x >> 18) & 7u, l1 = (r1.x >> 18) & 7u;
        unsigned l2 = (r2.x >> 18) & 7u, l3 = (r3.x >> 18) & 7u;
#pragma unroll
        for (int k = 0; k < 8; ++k) {
            acc[k] += (l0 == (unsigned)k) ? m0 : 0.f;
            acc[k] += (l1 == (unsigned)k) ? m1 : 0.f;
            acc[k] += (l2 == (unsigned)k) ? m2 : 0.f;
            acc[k] += (l3 == (unsigned)k) ? m3 : 0.f;
        }
    }
    for (; i < end; ++i) {
        uint2 r = payload[i];
        const float* __restrict__ t = (r.x & (1u << 17)) ? entity_emb : user_emb;
        float m = __uint_as_float(r.y) * t[(size_t)(r.x & 0x1FFFFu) * DIM + lane];
        unsigned l = (r.x >> 18) & 7u;
#pragma unroll
        for (int k = 0; k < 8; ++k) acc[k] += (l == (unsigned)k) ? m : 0.f;
    }

    long long base = (long long)wave * (8 * DIM) + lane;
#pragma unroll
    for (int k = 0; k < 8; ++k) out[base + (long long)k * DIM] = acc[k];
}

// pass3: direct atomics for overflow partitions (normally zero work)
__global__ void pass3_ovf(const uint2* __restrict__ payload,
                          const int* __restrict__ poffs,
                          const int* __restrict__ ovfcnt,
                          const int* __restrict__ ovflist,
                          const float* __restrict__ user_emb,
                          const float* __restrict__ entity_emb,
                          float* __restrict__ out) {
    int no = *ovfcnt;
    for (int o = 0; o < no; ++o) {
        int p = ovflist[o];
        int beg = poffs[p];
        int n = poffs[p + 1] - beg;
        for (int j = blockIdx.x * blockDim.x + threadIdx.x; j < n;
             j += gridDim.x * blockDim.x) {
            uint2 rec = payload[(size_t)beg + j];
            const float* tab = (rec.x & (1u << 17)) ? entity_emb : user_emb;
            float v = __uint_as_float(rec.y);
            int bucket = (p << 8) | (int)((rec.x >> 18) & 255u);
            const float* src = tab + (size_t)(rec.x & 0x1FFFFu) * DIM;
            float* dst = out + (size_t)bucket * DIM;
            for (int d = 0; d < DIM; ++d) atomicAdd(&dst[d], v * src[d]);
        }
    }
}

extern "C" void kernel_launch(void* const* d_in, const int* in_sizes, int n_in,
                              void* d_out, int out_size, void* d_ws, size_t ws_size,
                              hipStream_t stream) {
    const float* user_emb   = (const float*)d_in[0];  // [n_users, 64]
    const float* entity_emb = (const float*)d_in[1];  // [n_entities, 64]
    const int*   rows       = (const int*)d_in[2];
    const int*   cols       = (const int*)d_in[3];
    const float* vals       = (const float*)d_in[4];
    int nnz = in_sizes[2];
    int nu  = in_sizes[0] / DIM;   // 100000
    int ne  = in_sizes[1] / DIM;   // 50000
    int nb  = ne + nu;             // 150000 buckets
    int npart = (nb + PART_BUCKETS - 1) / PART_BUCKETS;   // 586
    int nbins = nb / 8;            // 18750
    int nbins_pad = npart * 32;    // 18752

    float* out = (float*)d_out;

    // ws (ints): pcnt[npart] | poffs[npart+1] | pcursor[npart] | offs[nbins_pad]
    //          | ends[nbins_pad] | ovfcnt[1] | ovflist[npart] | pad | payload[2*nnz]*8B
    size_t n_ints = (size_t)npart * 3 + 1 + (size_t)nbins_pad * 2 + 1 + npart;
    size_t pay_off_ints = (n_ints + 1) & ~(size_t)1;
    size_t need = pay_off_ints * 4 + (size_t)2 * nnz * 8;

    if (ws_size < need || (nb & 7) != 0 || npart > NPART_MAX ||
        nu > 131072 || ne > 131072) {
        float* entity_agg = out;
        float* user_agg   = out + (size_t)ne * DIM;
        hipMemsetAsync(d_out, 0, (size_t)out_size * sizeof(float), stream);
        long long total = (long long)nnz * DIM;
        int block = 256;
        long long grid = (total + block - 1) / block;
        coo_scatter_kernel<<<(int)grid, block, 0, stream>>>(
            user_emb, entity_emb, rows, cols, vals, entity_agg, user_agg, nnz);
        return;
    }

    int*   pcnt    = (int*)d_ws;
    int*   poffs   = pcnt + npart;           // npart+1
    int*   pcursor = poffs + npart + 1;
    int*   offs    = pcursor + npart;        // nbins_pad
    int*   ends    = offs + nbins_pad;       // nbins_pad
    int*   ovfcnt  = ends + nbins_pad;       // 1
    int*   ovflist = ovfcnt + 1;             // npart
    uint2* payload = (uint2*)((int*)d_ws + pay_off_ints);

    hipMemsetAsync(pcnt, 0, (size_t)npart * sizeof(int), stream);

    pass0_hist<<<512, 256, 0, stream>>>(rows, cols, pcnt, ne, nnz, npart);
    scan_parts<<<1, 256, 0, stream>>>(pcnt, poffs, pcursor, ovfcnt, npart);
    int g1 = (nnz + EPB - 1) / EPB;
    pass1_part<<<g1, 256, 0, stream>>>(rows, cols, vals, pcursor, payload, ne, nnz, npart);
    pass2_sort<<<npart, 256, 0, stream>>>(payload, poffs, offs, ends, ovfcnt, ovflist);
    int gAgg = (nbins + 3) / 4;
    agg_bins<<<gAgg, 256, 0, stream>>>(user_emb, entity_emb, offs, ends, payload, out, nbins);
    pass3_ovf<<<64, 256, 0, stream>>>(payload, poffs, ovfcnt, ovflist, user_emb, entity_emb, out);
}

// Round 8
// 327.906 us; speedup vs baseline: 26.9327x; 26.9327x over previous
//
#include <hip/hip_runtime.h>

#define DIM 64
#define PBITS 7
#define PART_BUCKETS 128      // buckets per partition
#define NPART_MAX 1184        // >= ceil(150016/128)=1172
#define BINS_PP 16            // 8-bucket bins per partition
#define EPT 16                // edges per thread, pass1
#define EPB (EPT * 256)       // 4096 edges per block, pass1
#define CAP2 8192             // max records per partition for in-place sort

// ---------------- fallback (round-1) atomic kernel ----------------
__global__ void coo_scatter_kernel(const float* __restrict__ user_emb,
                                   const float* __restrict__ entity_emb,
                                   const int* __restrict__ rows,
                                   const int* __restrict__ cols,
                                   const float* __restrict__ vals,
                                   float* __restrict__ entity_agg,
                                   float* __restrict__ user_agg,
                                   int nnz) {
    long long tid = (long long)blockIdx.x * blockDim.x + threadIdx.x;
    long long total = (long long)nnz * DIM;
    if (tid >= total) return;
    int edge = (int)(tid >> 6);
    int d = (int)(tid & 63);
    int r = rows[edge];
    int c = cols[edge];
    float v = vals[edge];
    atomicAdd(&entity_agg[c * DIM + d], v * user_emb[r * DIM + d]);
    atomicAdd(&user_agg[r * DIM + d], v * entity_emb[c * DIM + d]);
}

// record: uint2 { meta, valbits }; meta = (local7<<18) | (side<<17) | src
// bucket = partition*128 + local7. side 0: gather user_emb; side 1: entity_emb.
// bin-in-partition = local7 >> 3 (bits 21..24); bucket-in-bin = bits 18..20.

// pass0: per-partition histogram (LDS-staged)
__global__ __launch_bounds__(256) void pass0_hist(const int* __restrict__ rows,
                                                  const int* __restrict__ cols,
                                                  int* __restrict__ pcnt,
                                                  int ne, int nnz, int npart) {
    __shared__ int h[NPART_MAX];
    for (int t = threadIdx.x; t < npart; t += 256) h[t] = 0;
    __syncthreads();
    for (int i = blockIdx.x * blockDim.x + threadIdx.x; i < nnz;
         i += gridDim.x * blockDim.x) {
        int c = cols[i];
        int r = rows[i];
        atomicAdd(&h[c >> PBITS], 1);
        atomicAdd(&h[(ne + r) >> PBITS], 1);
    }
    __syncthreads();
    for (int t = threadIdx.x; t < npart; t += 256)
        if (h[t]) atomicAdd(&pcnt[t], h[t]);
}

// scan over npart partition counts (single block, parallel)
__global__ __launch_bounds__(256) void scan_parts(const int* __restrict__ pcnt,
                                                  int* __restrict__ poffs,
                                                  int* __restrict__ pcursor,
                                                  int* __restrict__ ovfcnt,
                                                  int npart) {
    __shared__ int sh[256];
    int t = threadIdx.x;
    int local[8];
    int s = 0;
#pragma unroll
    for (int j = 0; j < 8; ++j) {
        int idx = t * 8 + j;
        local[j] = (idx < npart) ? pcnt[idx] : 0;
        s += local[j];
    }
    sh[t] = s;
    for (int off = 1; off < 256; off <<= 1) {
        __syncthreads();
        int tmp = (t >= off) ? sh[t - off] : 0;
        __syncthreads();
        sh[t] += tmp;
    }
    __syncthreads();
    int run = sh[t] - s;   // exclusive prefix
#pragma unroll
    for (int j = 0; j < 8; ++j) {
        int idx = t * 8 + j;
        if (idx < npart) {
            poffs[idx] = run;
            pcursor[idx] = run;
            run += local[j];
        }
    }
    if (t == 255) poffs[npart] = sh[255];
    if (t == 0) *ovfcnt = 0;
}

// pass1: build records in registers, claim per-(block,partition) chunks,
// scatter. All writers of a chunk are one block -> mostly single-L2 lines.
__global__ __launch_bounds__(256) void pass1_part(const int* __restrict__ rows,
                                                  const int* __restrict__ cols,
                                                  const float* __restrict__ vals,
                                                  int* __restrict__ pcursor,
                                                  uint2* __restrict__ payload,
                                                  int ne, int nnz, int npart) {
    __shared__ int hist[NPART_MAX];
    __shared__ int cur[NPART_MAX];
    __shared__ int gbase[NPART_MAX];
    for (int t = threadIdx.x; t < npart; t += 256) { hist[t] = 0; cur[t] = 0; }
    __syncthreads();

    int base = blockIdx.x * EPB;
    uint2 rec[2 * EPT];
    int pid[2 * EPT];
#pragma unroll
    for (int k = 0; k < EPT; ++k) {
        int i = base + threadIdx.x + k * 256;
        if (i < nnz) {
            int r = rows[i];
            int c = cols[i];
            unsigned vb = __float_as_uint(vals[i]);
            int b2 = ne + r;
            int p1 = c >> PBITS;
            int p2 = b2 >> PBITS;
            rec[2 * k]     = make_uint2(((unsigned)(c & (PART_BUCKETS - 1)) << 18) | (unsigned)r, vb);
            rec[2 * k + 1] = make_uint2(((unsigned)(b2 & (PART_BUCKETS - 1)) << 18) | (1u << 17) | (unsigned)c, vb);
            pid[2 * k] = p1;
            pid[2 * k + 1] = p2;
            atomicAdd(&hist[p1], 1);
            atomicAdd(&hist[p2], 1);
        } else {
            pid[2 * k] = -1;
            pid[2 * k + 1] = -1;
        }
    }
    __syncthreads();
    for (int p = threadIdx.x; p < npart; p += 256) {
        int c_ = hist[p];
        if (c_) gbase[p] = atomicAdd(&pcursor[p], c_);
    }
    __syncthreads();
#pragma unroll
    for (int k = 0; k < 2 * EPT; ++k) {
        int p = pid[k];
        if (p >= 0) {
            int rank = atomicAdd(&cur[p], 1);
            payload[(size_t)gbase[p] + rank] = rec[k];
        }
    }
}

// pass2: one block per partition; in-place counting sort into 16 bins of
// 8 buckets; write per-bin [offs, ends).
__global__ __launch_bounds__(256) void pass2_sort(uint2* __restrict__ payload,
                                                  const int* __restrict__ poffs,
                                                  int* __restrict__ offs,
                                                  int* __restrict__ ends,
                                                  int* __restrict__ ovfcnt,
                                                  int* __restrict__ ovflist) {
    __shared__ int h[BINS_PP], sc[BINS_PP], cu[BINS_PP];
    int p = blockIdx.x;
    int beg = poffs[p];
    int n = poffs[p + 1] - beg;
    int t = threadIdx.x;
    if (t < BINS_PP) h[t] = 0;
    __syncthreads();

    if (n > CAP2) {   // ~43 sigma; handled by pass3 direct atomics
        if (t == 0) {
            int o = atomicAdd(ovfcnt, 1);
            ovflist[o] = p;
        }
        if (t < BINS_PP) { offs[p * BINS_PP + t] = beg; ends[p * BINS_PP + t] = beg; }
        return;
    }

    uint2 rec[32];
#pragma unroll
    for (int k = 0; k < 32; ++k) {
        int idx = t + k * 256;
        if (idx < n) {
            rec[k] = payload[(size_t)beg + idx];
            atomicAdd(&h[(rec[k].x >> 21) & (BINS_PP - 1)], 1);
        }
    }
    __syncthreads();
    if (t == 0) {
        int run = 0;
#pragma unroll
        for (int j = 0; j < BINS_PP; ++j) { sc[j] = run; run += h[j]; }
    }
    __syncthreads();
    if (t < BINS_PP) {
        offs[p * BINS_PP + t] = beg + sc[t];
        ends[p * BINS_PP + t] = beg + sc[t] + h[t];
        cu[t] = sc[t];
    }
    __syncthreads();   // all reads done (records in regs) -> in-place write safe
#pragma unroll
    for (int k = 0; k < 32; ++k) {
        int idx = t + k * 256;
        if (idx < n) {
            int bin = (rec[k].x >> 21) & (BINS_PP - 1);
            int rank = atomicAdd(&cu[bin], 1);
            payload[(size_t)beg + rank] = rec[k];
        }
    }
}

// agg: one WAVE per bin (8 buckets); register accumulators; lane = dim.
__global__ __launch_bounds__(256) void agg_bins(const float* __restrict__ user_emb,
                                                const float* __restrict__ entity_emb,
                                                const int* __restrict__ offs,
                                                const int* __restrict__ ends,
                                                const uint2* __restrict__ payload,
                                                float* __restrict__ out,
                                                int nbins) {
    int wave = blockIdx.x * 4 + (threadIdx.x >> 6);
    int lane = threadIdx.x & 63;
    if (wave >= nbins) return;
    int beg = offs[wave];
    int end = ends[wave];

    float acc[8];
#pragma unroll
    for (int k = 0; k < 8; ++k) acc[k] = 0.f;

    int i = beg;
    for (; i + 4 <= end; i += 4) {
        uint2 r0 = payload[i + 0];
        uint2 r1 = payload[i + 1];
        uint2 r2 = payload[i + 2];
        uint2 r3 = payload[i + 3];
        const float* __restrict__ t0 = (r0.x & (1u << 17)) ? entity_emb : user_emb;
        const float* __restrict__ t1 = (r1.x & (1u << 17)) ? entity_emb : user_emb;
        const float* __restrict__ t2 = (r2.x & (1u << 17)) ? entity_emb : user_emb;
        const float* __restrict__ t3 = (r3.x & (1u << 17)) ? entity_emb : user_emb;
        float e0 = t0[(size_t)(r0.x & 0x1FFFFu) * DIM + lane];
        float e1 = t1[(size_t)(r1.x & 0x1FFFFu) * DIM + lane];
        float e2 = t2[(size_t)(r2.x & 0x1FFFFu) * DIM + lane];
        float e3 = t3[(size_t)(r3.x & 0x1FFFFu) * DIM + lane];
        float m0 = __uint_as_float(r0.y) * e0;
        float m1 = __uint_as_float(r1.y) * e1;
        float m2 = __uint_as_float(r2.y) * e2;
        float m3 = __uint_as_float(r3.y) * e3;
        unsigned l0 = (r0.x >> 18) & 7u, l1 = (r1.x >> 18) & 7u;
        unsigned l2 = (r2.x >> 18) & 7u, l3 = (r3.x >> 18) & 7u;
#pragma unroll
        for (int k = 0; k < 8; ++k) {
            acc[k] += (l0 == (unsigned)k) ? m0 : 0.f;
            acc[k] += (l1 == (unsigned)k) ? m1 : 0.f;
            acc[k] += (l2 == (unsigned)k) ? m2 : 0.f;
            acc[k] += (l3 == (unsigned)k) ? m3 : 0.f;
        }
    }
    for (; i < end; ++i) {
        uint2 r = payload[i];
        const float* __restrict__ t = (r.x & (1u << 17)) ? entity_emb : user_emb;
        float m = __uint_as_float(r.y) * t[(size_t)(r.x & 0x1FFFFu) * DIM + lane];
        unsigned l = (r.x >> 18) & 7u;
#pragma unroll
        for (int k = 0; k < 8; ++k) acc[k] += (l == (unsigned)k) ? m : 0.f;
    }

    long long base = (long long)wave * (8 * DIM) + lane;
#pragma unroll
    for (int k = 0; k < 8; ++k) out[base + (long long)k * DIM] = acc[k];
}

// pass3: direct atomics for overflow partitions (normally zero work)
__global__ void pass3_ovf(const uint2* __restrict__ payload,
                          const int* __restrict__ poffs,
                          const int* __restrict__ ovfcnt,
                          const int* __restrict__ ovflist,
                          const float* __restrict__ user_emb,
                          const float* __restrict__ entity_emb,
                          float* __restrict__ out) {
    int no = *ovfcnt;
    for (int o = 0; o < no; ++o) {
        int p = ovflist[o];
        int beg = poffs[p];
        int n = poffs[p + 1] - beg;
        for (int j = blockIdx.x * blockDim.x + threadIdx.x; j < n * 16;
             j += gridDim.x * blockDim.x) {
            uint2 rec = payload[(size_t)beg + (j >> 4)];
            int d4 = (j & 15) * 4;
            const float* tab = (rec.x & (1u << 17)) ? entity_emb : user_emb;
            float v = __uint_as_float(rec.y);
            int bucket = (p << PBITS) | (int)((rec.x >> 18) & (PART_BUCKETS - 1));
            const float* src = tab + (size_t)(rec.x & 0x1FFFFu) * DIM + d4;
            float* dst = out + (size_t)bucket * DIM + d4;
            for (int d = 0; d < 4; ++d) atomicAdd(&dst[d], v * src[d]);
        }
    }
}

extern "C" void kernel_launch(void* const* d_in, const int* in_sizes, int n_in,
                              void* d_out, int out_size, void* d_ws, size_t ws_size,
                              hipStream_t stream) {
    const float* user_emb   = (const float*)d_in[0];  // [n_users, 64]
    const float* entity_emb = (const float*)d_in[1];  // [n_entities, 64]
    const int*   rows       = (const int*)d_in[2];
    const int*   cols       = (const int*)d_in[3];
    const float* vals       = (const float*)d_in[4];
    int nnz = in_sizes[2];
    int nu  = in_sizes[0] / DIM;   // 100000
    int ne  = in_sizes[1] / DIM;   // 50000
    int nb  = ne + nu;             // 150000 buckets
    int npart = (nb + PART_BUCKETS - 1) / PART_BUCKETS;   // 1172
    int nbins = nb / 8;            // 18750
    int nbins_pad = npart * BINS_PP;   // 18752

    float* out = (float*)d_out;

    // ws (ints): pcnt[npart] | poffs[npart+1] | pcursor[npart] | offs[nbins_pad]
    //          | ends[nbins_pad] | ovfcnt[1] | ovflist[npart] | pad | payload[2*nnz]*8B
    size_t n_ints = (size_t)npart * 3 + 1 + (size_t)nbins_pad * 2 + 1 + npart;
    size_t pay_off_ints = (n_ints + 1) & ~(size_t)1;
    size_t need = pay_off_ints * 4 + (size_t)2 * nnz * 8;

    if (ws_size < need || (nb & 7) != 0 || npart > NPART_MAX ||
        nu > 131072 || ne > 131072) {
        float* entity_agg = out;
        float* user_agg   = out + (size_t)ne * DIM;
        hipMemsetAsync(d_out, 0, (size_t)out_size * sizeof(float), stream);
        long long total = (long long)nnz * DIM;
        int block = 256;
        long long grid = (total + block - 1) / block;
        coo_scatter_kernel<<<(int)grid, block, 0, stream>>>(
            user_emb, entity_emb, rows, cols, vals, entity_agg, user_agg, nnz);
        return;
    }

    int*   pcnt    = (int*)d_ws;
    int*   poffs   = pcnt + npart;           // npart+1
    int*   pcursor = poffs + npart + 1;
    int*   offs    = pcursor + npart;        // nbins_pad
    int*   ends    = offs + nbins_pad;       // nbins_pad
    int*   ovfcnt  = ends + nbins_pad;       // 1
    int*   ovflist = ovfcnt + 1;             // npart
    uint2* payload = (uint2*)((int*)d_ws + pay_off_ints);

    hipMemsetAsync(pcnt, 0, (size_t)npart * sizeof(int), stream);

    pass0_hist<<<512, 256, 0, stream>>>(rows, cols, pcnt, ne, nnz, npart);
    scan_parts<<<1, 256, 0, stream>>>(pcnt, poffs, pcursor, ovfcnt, npart);
    int g1 = (nnz + EPB - 1) / EPB;
    pass1_part<<<g1, 256, 0, stream>>>(rows, cols, vals, pcursor, payload, ne, nnz, npart);
    pass2_sort<<<npart, 256, 0, stream>>>(payload, poffs, offs, ends, ovfcnt, ovflist);
    int gAgg = (nbins + 3) / 4;
    agg_bins<<<gAgg, 256, 0, stream>>>(user_emb, entity_emb, offs, ends, payload, out, nbins);
    pass3_ovf<<<64, 256, 0, stream>>>(payload, poffs, ovfcnt, ovflist, user_emb, entity_emb, out);
}

// Round 9
// 264.508 us; speedup vs baseline: 33.3881x; 1.2397x over previous
//
#include <hip/hip_runtime.h>

#define DIM 64
#define PBITS 7
#define PART_BUCKETS 128      // buckets per partition
#define NPART_MAX 1184        // >= ceil(150016/128)=1172
#define EPT 16                // edges per thread, pass1
#define EPB (EPT * 256)       // 4096 edges per block, pass1
#define CAP2 8192             // max records per partition for in-place sort

// ---------------- fallback (round-1) atomic kernel ----------------
__global__ void coo_scatter_kernel(const float* __restrict__ user_emb,
                                   const float* __restrict__ entity_emb,
                                   const int* __restrict__ rows,
                                   const int* __restrict__ cols,
                                   const float* __restrict__ vals,
                                   float* __restrict__ entity_agg,
                                   float* __restrict__ user_agg,
                                   int nnz) {
    long long tid = (long long)blockIdx.x * blockDim.x + threadIdx.x;
    long long total = (long long)nnz * DIM;
    if (tid >= total) return;
    int edge = (int)(tid >> 6);
    int d = (int)(tid & 63);
    int r = rows[edge];
    int c = cols[edge];
    float v = vals[edge];
    atomicAdd(&entity_agg[c * DIM + d], v * user_emb[r * DIM + d]);
    atomicAdd(&user_agg[r * DIM + d], v * entity_emb[c * DIM + d]);
}

// record: uint2 { meta, valbits }; meta = (local7<<18) | (side<<17) | src
// bucket = partition*128 + local7. side 0: gather user_emb; side 1: entity_emb.

// pass0: per-partition histogram (LDS-staged)
__global__ __launch_bounds__(256) void pass0_hist(const int* __restrict__ rows,
                                                  const int* __restrict__ cols,
                                                  int* __restrict__ pcnt,
                                                  int ne, int nnz, int npart) {
    __shared__ int h[NPART_MAX];
    for (int t = threadIdx.x; t < npart; t += 256) h[t] = 0;
    __syncthreads();
    for (int i = blockIdx.x * blockDim.x + threadIdx.x; i < nnz;
         i += gridDim.x * blockDim.x) {
        int c = cols[i];
        int r = rows[i];
        atomicAdd(&h[c >> PBITS], 1);
        atomicAdd(&h[(ne + r) >> PBITS], 1);
    }
    __syncthreads();
    for (int t = threadIdx.x; t < npart; t += 256)
        if (h[t]) atomicAdd(&pcnt[t], h[t]);
}

// scan over npart partition counts (single block, parallel)
__global__ __launch_bounds__(256) void scan_parts(const int* __restrict__ pcnt,
                                                  int* __restrict__ poffs,
                                                  int* __restrict__ pcursor,
                                                  int* __restrict__ ovfcnt,
                                                  int npart) {
    __shared__ int sh[256];
    int t = threadIdx.x;
    int local[8];
    int s = 0;
#pragma unroll
    for (int j = 0; j < 8; ++j) {
        int idx = t * 8 + j;
        local[j] = (idx < npart) ? pcnt[idx] : 0;
        s += local[j];
    }
    sh[t] = s;
    for (int off = 1; off < 256; off <<= 1) {
        __syncthreads();
        int tmp = (t >= off) ? sh[t - off] : 0;
        __syncthreads();
        sh[t] += tmp;
    }
    __syncthreads();
    int run = sh[t] - s;   // exclusive prefix
#pragma unroll
    for (int j = 0; j < 8; ++j) {
        int idx = t * 8 + j;
        if (idx < npart) {
            poffs[idx] = run;
            pcursor[idx] = run;
            run += local[j];
        }
    }
    if (t == 255) poffs[npart] = sh[255];
    if (t == 0) *ovfcnt = 0;
}

// pass1: build records in registers, claim per-(block,partition) chunks,
// scatter. All writers of a chunk are one block -> mostly single-L2 lines.
__global__ __launch_bounds__(256) void pass1_part(const int* __restrict__ rows,
                                                  const int* __restrict__ cols,
                                                  const float* __restrict__ vals,
                                                  int* __restrict__ pcursor,
                                                  uint2* __restrict__ payload,
                                                  int ne, int nnz, int npart) {
    __shared__ int hist[NPART_MAX];
    __shared__ int cur[NPART_MAX];
    __shared__ int gbase[NPART_MAX];
    for (int t = threadIdx.x; t < npart; t += 256) { hist[t] = 0; cur[t] = 0; }
    __syncthreads();

    int base = blockIdx.x * EPB;
    uint2 rec[2 * EPT];
    int pid[2 * EPT];
#pragma unroll
    for (int k = 0; k < EPT; ++k) {
        int i = base + threadIdx.x + k * 256;
        if (i < nnz) {
            int r = rows[i];
            int c = cols[i];
            unsigned vb = __float_as_uint(vals[i]);
            int b2 = ne + r;
            int p1 = c >> PBITS;
            int p2 = b2 >> PBITS;
            rec[2 * k]     = make_uint2(((unsigned)(c & (PART_BUCKETS - 1)) << 18) | (unsigned)r, vb);
            rec[2 * k + 1] = make_uint2(((unsigned)(b2 & (PART_BUCKETS - 1)) << 18) | (1u << 17) | (unsigned)c, vb);
            pid[2 * k] = p1;
            pid[2 * k + 1] = p2;
            atomicAdd(&hist[p1], 1);
            atomicAdd(&hist[p2], 1);
        } else {
            pid[2 * k] = -1;
            pid[2 * k + 1] = -1;
        }
    }
    __syncthreads();
    for (int p = threadIdx.x; p < npart; p += 256) {
        int c_ = hist[p];
        if (c_) gbase[p] = atomicAdd(&pcursor[p], c_);
    }
    __syncthreads();
#pragma unroll
    for (int k = 0; k < 2 * EPT; ++k) {
        int p = pid[k];
        if (p >= 0) {
            int rank = atomicAdd(&cur[p], 1);
            payload[(size_t)gbase[p] + rank] = rec[k];
        }
    }
}

// pass2: one block per partition; in-place counting sort into ALL 128
// buckets; write per-bucket [offs, ends). Select-free agg follows.
__global__ __launch_bounds__(256) void pass2_sort(uint2* __restrict__ payload,
                                                  const int* __restrict__ poffs,
                                                  int* __restrict__ offs,
                                                  int* __restrict__ ends,
                                                  int* __restrict__ ovfcnt,
                                                  int* __restrict__ ovflist) {
    __shared__ int h[PART_BUCKETS], sc[PART_BUCKETS], cu[PART_BUCKETS];
    int p = blockIdx.x;
    int beg = poffs[p];
    int n = poffs[p + 1] - beg;
    int t = threadIdx.x;
    if (t < PART_BUCKETS) h[t] = 0;
    __syncthreads();

    if (n > CAP2) {   // ~43 sigma; handled by pass3 direct atomics
        if (t == 0) {
            int o = atomicAdd(ovfcnt, 1);
            ovflist[o] = p;
        }
        if (t < PART_BUCKETS) {
            offs[p * PART_BUCKETS + t] = beg;
            ends[p * PART_BUCKETS + t] = beg;
        }
        return;
    }

    uint2 rec[32];
#pragma unroll
    for (int k = 0; k < 32; ++k) {
        int idx = t + k * 256;
        if (idx < n) {
            rec[k] = payload[(size_t)beg + idx];
            atomicAdd(&h[(rec[k].x >> 18) & (PART_BUCKETS - 1)], 1);
        }
    }
    __syncthreads();
    if (t == 0) {
        int run = 0;
#pragma unroll
        for (int j = 0; j < PART_BUCKETS; ++j) { sc[j] = run; run += h[j]; }
    }
    __syncthreads();
    if (t < PART_BUCKETS) {
        offs[p * PART_BUCKETS + t] = beg + sc[t];
        ends[p * PART_BUCKETS + t] = beg + sc[t] + h[t];
        cu[t] = sc[t];
    }
    __syncthreads();   // all reads done (records in regs) -> in-place write safe
#pragma unroll
    for (int k = 0; k < 32; ++k) {
        int idx = t + k * 256;
        if (idx < n) {
            int bucket = (rec[k].x >> 18) & (PART_BUCKETS - 1);
            int rank = atomicAdd(&cu[bucket], 1);
            payload[(size_t)beg + rank] = rec[k];
        }
    }
}

// agg: one WAVE per bucket; single accumulator (4 partials for ILP); lane = dim.
__global__ __launch_bounds__(256) void agg_buckets(const float* __restrict__ user_emb,
                                                   const float* __restrict__ entity_emb,
                                                   const int* __restrict__ offs,
                                                   const int* __restrict__ ends,
                                                   const uint2* __restrict__ payload,
                                                   float* __restrict__ out,
                                                   int nbuckets) {
    int bucket = blockIdx.x * 4 + (threadIdx.x >> 6);
    int lane = threadIdx.x & 63;
    if (bucket >= nbuckets) return;
    int beg = offs[bucket];
    int end = ends[bucket];

    float a0 = 0.f, a1 = 0.f, a2 = 0.f, a3 = 0.f;
    int i = beg;
    for (; i + 4 <= end; i += 4) {
        uint2 r0 = payload[i + 0];
        uint2 r1 = payload[i + 1];
        uint2 r2 = payload[i + 2];
        uint2 r3 = payload[i + 3];
        const float* __restrict__ t0 = (r0.x & (1u << 17)) ? entity_emb : user_emb;
        const float* __restrict__ t1 = (r1.x & (1u << 17)) ? entity_emb : user_emb;
        const float* __restrict__ t2 = (r2.x & (1u << 17)) ? entity_emb : user_emb;
        const float* __restrict__ t3 = (r3.x & (1u << 17)) ? entity_emb : user_emb;
        float e0 = t0[(size_t)(r0.x & 0x1FFFFu) * DIM + lane];
        float e1 = t1[(size_t)(r1.x & 0x1FFFFu) * DIM + lane];
        float e2 = t2[(size_t)(r2.x & 0x1FFFFu) * DIM + lane];
        float e3 = t3[(size_t)(r3.x & 0x1FFFFu) * DIM + lane];
        a0 += __uint_as_float(r0.y) * e0;
        a1 += __uint_as_float(r1.y) * e1;
        a2 += __uint_as_float(r2.y) * e2;
        a3 += __uint_as_float(r3.y) * e3;
    }
    for (; i < end; ++i) {
        uint2 r = payload[i];
        const float* __restrict__ t = (r.x & (1u << 17)) ? entity_emb : user_emb;
        a0 += __uint_as_float(r.y) * t[(size_t)(r.x & 0x1FFFFu) * DIM + lane];
    }
    out[(size_t)bucket * DIM + lane] = (a0 + a1) + (a2 + a3);
}

// pass3: direct atomics for overflow partitions (normally zero work)
__global__ void pass3_ovf(const uint2* __restrict__ payload,
                          const int* __restrict__ poffs,
                          const int* __restrict__ ovfcnt,
                          const int* __restrict__ ovflist,
                          const float* __restrict__ user_emb,
                          const float* __restrict__ entity_emb,
                          float* __restrict__ out) {
    int no = *ovfcnt;
    for (int o = 0; o < no; ++o) {
        int p = ovflist[o];
        int beg = poffs[p];
        int n = poffs[p + 1] - beg;
        for (int j = blockIdx.x * blockDim.x + threadIdx.x; j < n * 16;
             j += gridDim.x * blockDim.x) {
            uint2 rec = payload[(size_t)beg + (j >> 4)];
            int d4 = (j & 15) * 4;
            const float* tab = (rec.x & (1u << 17)) ? entity_emb : user_emb;
            float v = __uint_as_float(rec.y);
            int bucket = (p << PBITS) | (int)((rec.x >> 18) & (PART_BUCKETS - 1));
            const float* src = tab + (size_t)(rec.x & 0x1FFFFu) * DIM + d4;
            float* dst = out + (size_t)bucket * DIM + d4;
            for (int d = 0; d < 4; ++d) atomicAdd(&dst[d], v * src[d]);
        }
    }
}

extern "C" void kernel_launch(void* const* d_in, const int* in_sizes, int n_in,
                              void* d_out, int out_size, void* d_ws, size_t ws_size,
                              hipStream_t stream) {
    const float* user_emb   = (const float*)d_in[0];  // [n_users, 64]
    const float* entity_emb = (const float*)d_in[1];  // [n_entities, 64]
    const int*   rows       = (const int*)d_in[2];
    const int*   cols       = (const int*)d_in[3];
    const float* vals       = (const float*)d_in[4];
    int nnz = in_sizes[2];
    int nu  = in_sizes[0] / DIM;   // 100000
    int ne  = in_sizes[1] / DIM;   // 50000
    int nb  = ne + nu;             // 150000 buckets
    int npart = (nb + PART_BUCKETS - 1) / PART_BUCKETS;   // 1172
    int nbk_pad = npart * PART_BUCKETS;   // 150016

    float* out = (float*)d_out;

    // ws (ints): pcnt[npart] | poffs[npart+1] | pcursor[npart] | offs[nbk_pad]
    //          | ends[nbk_pad] | ovfcnt[1] | ovflist[npart] | pad | payload[2*nnz]*8B
    size_t n_ints = (size_t)npart * 3 + 1 + (size_t)nbk_pad * 2 + 1 + npart;
    size_t pay_off_ints = (n_ints + 1) & ~(size_t)1;
    size_t need = pay_off_ints * 4 + (size_t)2 * nnz * 8;

    if (ws_size < need || npart > NPART_MAX || nu > 131072 || ne > 131072) {
        float* entity_agg = out;
        float* user_agg   = out + (size_t)ne * DIM;
        hipMemsetAsync(d_out, 0, (size_t)out_size * sizeof(float), stream);
        long long total = (long long)nnz * DIM;
        int block = 256;
        long long grid = (total + block - 1) / block;
        coo_scatter_kernel<<<(int)grid, block, 0, stream>>>(
            user_emb, entity_emb, rows, cols, vals, entity_agg, user_agg, nnz);
        return;
    }

    int*   pcnt    = (int*)d_ws;
    int*   poffs   = pcnt + npart;           // npart+1
    int*   pcursor = poffs + npart + 1;
    int*   offs    = pcursor + npart;        // nbk_pad
    int*   ends    = offs + nbk_pad;         // nbk_pad
    int*   ovfcnt  = ends + nbk_pad;         // 1
    int*   ovflist = ovfcnt + 1;             // npart
    uint2* payload = (uint2*)((int*)d_ws + pay_off_ints);

    hipMemsetAsync(pcnt, 0, (size_t)npart * sizeof(int), stream);

    pass0_hist<<<512, 256, 0, stream>>>(rows, cols, pcnt, ne, nnz, npart);
    scan_parts<<<1, 256, 0, stream>>>(pcnt, poffs, pcursor, ovfcnt, npart);
    int g1 = (nnz + EPB - 1) / EPB;
    pass1_part<<<g1, 256, 0, stream>>>(rows, cols, vals, pcursor, payload, ne, nnz, npart);
    pass2_sort<<<npart, 256, 0, stream>>>(payload, poffs, offs, ends, ovfcnt, ovflist);
    int gAgg = (nb + 3) / 4;   // one wave per bucket, 4 waves/block
    agg_buckets<<<gAgg, 256, 0, stream>>>(user_emb, entity_emb, offs, ends, payload, out, nb);
    pass3_ovf<<<64, 256, 0, stream>>>(payload, poffs, ovfcnt, ovflist, user_emb, entity_emb, out);
}

// Round 10
// 240.415 us; speedup vs baseline: 36.7341x; 1.1002x over previous
//
#include <hip/hip_runtime.h>

#define DIM 64
#define PBITS 7
#define PART_BUCKETS 128      // buckets per partition
#define NPART_MAX 1184        // >= ceil(150016/128)=1172
#define EPT 16                // edges per thread, pass1
#define EPB (EPT * 256)       // 4096 edges per block, pass1
#define CAP2 8192             // max records per partition for in-place sort

// ---------------- fallback (round-1) atomic kernel ----------------
__global__ void coo_scatter_kernel(const float* __restrict__ user_emb,
                                   const float* __restrict__ entity_emb,
                                   const int* __restrict__ rows,
                                   const int* __restrict__ cols,
                                   const float* __restrict__ vals,
                                   float* __restrict__ entity_agg,
                                   float* __restrict__ user_agg,
                                   int nnz) {
    long long tid = (long long)blockIdx.x * blockDim.x + threadIdx.x;
    long long total = (long long)nnz * DIM;
    if (tid >= total) return;
    int edge = (int)(tid >> 6);
    int d = (int)(tid & 63);
    int r = rows[edge];
    int c = cols[edge];
    float v = vals[edge];
    atomicAdd(&entity_agg[c * DIM + d], v * user_emb[r * DIM + d]);
    atomicAdd(&user_agg[r * DIM + d], v * entity_emb[c * DIM + d]);
}

// record: uint2 { meta, valbits }; meta = (local7<<18) | (side<<17) | src
// bucket = partition*128 + local7. side 0: gather user_emb; side 1: entity_emb.

// pass0: per-partition histogram (LDS-staged)
__global__ __launch_bounds__(256) void pass0_hist(const int* __restrict__ rows,
                                                  const int* __restrict__ cols,
                                                  int* __restrict__ pcnt,
                                                  int ne, int nnz, int npart) {
    __shared__ int h[NPART_MAX];
    for (int t = threadIdx.x; t < npart; t += 256) h[t] = 0;
    __syncthreads();
    for (int i = blockIdx.x * blockDim.x + threadIdx.x; i < nnz;
         i += gridDim.x * blockDim.x) {
        int c = cols[i];
        int r = rows[i];
        atomicAdd(&h[c >> PBITS], 1);
        atomicAdd(&h[(ne + r) >> PBITS], 1);
    }
    __syncthreads();
    for (int t = threadIdx.x; t < npart; t += 256)
        if (h[t]) atomicAdd(&pcnt[t], h[t]);
}

// scan over npart partition counts (single block, parallel)
__global__ __launch_bounds__(256) void scan_parts(const int* __restrict__ pcnt,
                                                  int* __restrict__ poffs,
                                                  int* __restrict__ pcursor,
                                                  int* __restrict__ ovfcnt,
                                                  int npart) {
    __shared__ int sh[256];
    int t = threadIdx.x;
    int local[8];
    int s = 0;
#pragma unroll
    for (int j = 0; j < 8; ++j) {
        int idx = t * 8 + j;
        local[j] = (idx < npart) ? pcnt[idx] : 0;
        s += local[j];
    }
    sh[t] = s;
    for (int off = 1; off < 256; off <<= 1) {
        __syncthreads();
        int tmp = (t >= off) ? sh[t - off] : 0;
        __syncthreads();
        sh[t] += tmp;
    }
    __syncthreads();
    int run = sh[t] - s;   // exclusive prefix
#pragma unroll
    for (int j = 0; j < 8; ++j) {
        int idx = t * 8 + j;
        if (idx < npart) {
            poffs[idx] = run;
            pcursor[idx] = run;
            run += local[j];
        }
    }
    if (t == 255) poffs[npart] = sh[255];
    if (t == 0) *ovfcnt = 0;
}

// pass1: build records in registers, claim per-(block,partition) chunks,
// scatter. All writers of a chunk are one block -> mostly single-L2 lines.
__global__ __launch_bounds__(256) void pass1_part(const int* __restrict__ rows,
                                                  const int* __restrict__ cols,
                                                  const float* __restrict__ vals,
                                                  int* __restrict__ pcursor,
                                                  uint2* __restrict__ payload,
                                                  int ne, int nnz, int npart) {
    __shared__ int hist[NPART_MAX];
    __shared__ int cur[NPART_MAX];
    __shared__ int gbase[NPART_MAX];
    for (int t = threadIdx.x; t < npart; t += 256) { hist[t] = 0; cur[t] = 0; }
    __syncthreads();

    int base = blockIdx.x * EPB;
    uint2 rec[2 * EPT];
    int pid[2 * EPT];
#pragma unroll
    for (int k = 0; k < EPT; ++k) {
        int i = base + threadIdx.x + k * 256;
        if (i < nnz) {
            int r = rows[i];
            int c = cols[i];
            unsigned vb = __float_as_uint(vals[i]);
            int b2 = ne + r;
            int p1 = c >> PBITS;
            int p2 = b2 >> PBITS;
            rec[2 * k]     = make_uint2(((unsigned)(c & (PART_BUCKETS - 1)) << 18) | (unsigned)r, vb);
            rec[2 * k + 1] = make_uint2(((unsigned)(b2 & (PART_BUCKETS - 1)) << 18) | (1u << 17) | (unsigned)c, vb);
            pid[2 * k] = p1;
            pid[2 * k + 1] = p2;
            atomicAdd(&hist[p1], 1);
            atomicAdd(&hist[p2], 1);
        } else {
            pid[2 * k] = -1;
            pid[2 * k + 1] = -1;
        }
    }
    __syncthreads();
    for (int p = threadIdx.x; p < npart; p += 256) {
        int c_ = hist[p];
        if (c_) gbase[p] = atomicAdd(&pcursor[p], c_);
    }
    __syncthreads();
#pragma unroll
    for (int k = 0; k < 2 * EPT; ++k) {
        int p = pid[k];
        if (p >= 0) {
            int rank = atomicAdd(&cur[p], 1);
            payload[(size_t)gbase[p] + rank] = rec[k];
        }
    }
}

// pass2: one block per partition; in-place counting sort into ALL 128
// buckets; write per-bucket [offs, ends). Select-free agg follows.
__global__ __launch_bounds__(256) void pass2_sort(uint2* __restrict__ payload,
                                                  const int* __restrict__ poffs,
                                                  int* __restrict__ offs,
                                                  int* __restrict__ ends,
                                                  int* __restrict__ ovfcnt,
                                                  int* __restrict__ ovflist) {
    __shared__ int h[PART_BUCKETS], sc[PART_BUCKETS], cu[PART_BUCKETS];
    int p = blockIdx.x;
    int beg = poffs[p];
    int n = poffs[p + 1] - beg;
    int t = threadIdx.x;
    if (t < PART_BUCKETS) h[t] = 0;
    __syncthreads();

    if (n > CAP2) {   // ~43 sigma; handled by pass3 direct atomics
        if (t == 0) {
            int o = atomicAdd(ovfcnt, 1);
            ovflist[o] = p;
        }
        if (t < PART_BUCKETS) {
            offs[p * PART_BUCKETS + t] = beg;
            ends[p * PART_BUCKETS + t] = beg;
        }
        return;
    }

    uint2 rec[32];
#pragma unroll
    for (int k = 0; k < 32; ++k) {
        int idx = t + k * 256;
        if (idx < n) {
            rec[k] = payload[(size_t)beg + idx];
            atomicAdd(&h[(rec[k].x >> 18) & (PART_BUCKETS - 1)], 1);
        }
    }
    __syncthreads();
    if (t == 0) {
        int run = 0;
#pragma unroll
        for (int j = 0; j < PART_BUCKETS; ++j) { sc[j] = run; run += h[j]; }
    }
    __syncthreads();
    if (t < PART_BUCKETS) {
        offs[p * PART_BUCKETS + t] = beg + sc[t];
        ends[p * PART_BUCKETS + t] = beg + sc[t] + h[t];
        cu[t] = sc[t];
    }
    __syncthreads();   // all reads done (records in regs) -> in-place write safe
#pragma unroll
    for (int k = 0; k < 32; ++k) {
        int idx = t + k * 256;
        if (idx < n) {
            int bucket = (rec[k].x >> 18) & (PART_BUCKETS - 1);
            int rank = atomicAdd(&cu[bucket], 1);
            payload[(size_t)beg + rank] = rec[k];
        }
    }
}

// agg: one WAVE per bucket; 4x16-lane groups each own one record and gather
// its 256B row as 16 x float4 (dwordx4). shfl_xor folds groups at the end.
__global__ __launch_bounds__(256) void agg_buckets(const float* __restrict__ user_emb,
                                                   const float* __restrict__ entity_emb,
                                                   const int* __restrict__ offs,
                                                   const int* __restrict__ ends,
                                                   const uint2* __restrict__ payload,
                                                   float* __restrict__ out,
                                                   int nbuckets) {
    int bucket = blockIdx.x * 4 + (threadIdx.x >> 6);
    int lane = threadIdx.x & 63;
    if (bucket >= nbuckets) return;
    int beg = offs[bucket];
    int end = ends[bucket];

    int grp = lane >> 4;      // which record of the quad
    int sub = lane & 15;      // float4 slot within the row

    float ax0 = 0.f, ay0 = 0.f, az0 = 0.f, aw0 = 0.f;
    float ax1 = 0.f, ay1 = 0.f, az1 = 0.f, aw1 = 0.f;

    int i = beg;
    for (; i + 8 <= end; i += 8) {
        uint2 rA = payload[i + grp];
        uint2 rB = payload[i + 4 + grp];
        const float* __restrict__ tA = (rA.x & (1u << 17)) ? entity_emb : user_emb;
        const float* __restrict__ tB = (rB.x & (1u << 17)) ? entity_emb : user_emb;
        const float4 eA = *(const float4*)(tA + (size_t)(rA.x & 0x1FFFFu) * DIM + sub * 4);
        const float4 eB = *(const float4*)(tB + (size_t)(rB.x & 0x1FFFFu) * DIM + sub * 4);
        float vA = __uint_as_float(rA.y);
        float vB = __uint_as_float(rB.y);
        ax0 += vA * eA.x; ay0 += vA * eA.y; az0 += vA * eA.z; aw0 += vA * eA.w;
        ax1 += vB * eB.x; ay1 += vB * eB.y; az1 += vB * eB.z; aw1 += vB * eB.w;
    }
    for (; i < end; i += 4) {
        int j = i + grp;
        bool valid = j < end;
        uint2 r = payload[valid ? j : end - 1];
        const float* __restrict__ t = (r.x & (1u << 17)) ? entity_emb : user_emb;
        const float4 e = *(const float4*)(t + (size_t)(r.x & 0x1FFFFu) * DIM + sub * 4);
        float v = valid ? __uint_as_float(r.y) : 0.f;
        ax0 += v * e.x; ay0 += v * e.y; az0 += v * e.z; aw0 += v * e.w;
    }

    ax0 += ax1; ay0 += ay1; az0 += az1; aw0 += aw1;
    // fold the 4 lane-groups: lanes l, l^16, l^32, l^48 hold the same dims
    ax0 += __shfl_xor(ax0, 16, 64); ay0 += __shfl_xor(ay0, 16, 64);
    az0 += __shfl_xor(az0, 16, 64); aw0 += __shfl_xor(aw0, 16, 64);
    ax0 += __shfl_xor(ax0, 32, 64); ay0 += __shfl_xor(ay0, 32, 64);
    az0 += __shfl_xor(az0, 32, 64); aw0 += __shfl_xor(aw0, 32, 64);

    if (grp == 0) {
        float4 res = make_float4(ax0, ay0, az0, aw0);
        *(float4*)(out + (size_t)bucket * DIM + sub * 4) = res;
    }
}

// pass3: direct atomics for overflow partitions (normally zero work)
__global__ void pass3_ovf(const uint2* __restrict__ payload,
                          const int* __restrict__ poffs,
                          const int* __restrict__ ovfcnt,
                          const int* __restrict__ ovflist,
                          const float* __restrict__ user_emb,
                          const float* __restrict__ entity_emb,
                          float* __restrict__ out) {
    int no = *ovfcnt;
    for (int o = 0; o < no; ++o) {
        int p = ovflist[o];
        int beg = poffs[p];
        int n = poffs[p + 1] - beg;
        for (int j = blockIdx.x * blockDim.x + threadIdx.x; j < n * 16;
             j += gridDim.x * blockDim.x) {
            uint2 rec = payload[(size_t)beg + (j >> 4)];
            int d4 = (j & 15) * 4;
            const float* tab = (rec.x & (1u << 17)) ? entity_emb : user_emb;
            float v = __uint_as_float(rec.y);
            int bucket = (p << PBITS) | (int)((rec.x >> 18) & (PART_BUCKETS - 1));
            const float* src = tab + (size_t)(rec.x & 0x1FFFFu) * DIM + d4;
            float* dst = out + (size_t)bucket * DIM + d4;
            for (int d = 0; d < 4; ++d) atomicAdd(&dst[d], v * src[d]);
        }
    }
}

extern "C" void kernel_launch(void* const* d_in, const int* in_sizes, int n_in,
                              void* d_out, int out_size, void* d_ws, size_t ws_size,
                              hipStream_t stream) {
    const float* user_emb   = (const float*)d_in[0];  // [n_users, 64]
    const float* entity_emb = (const float*)d_in[1];  // [n_entities, 64]
    const int*   rows       = (const int*)d_in[2];
    const int*   cols       = (const int*)d_in[3];
    const float* vals       = (const float*)d_in[4];
    int nnz = in_sizes[2];
    int nu  = in_sizes[0] / DIM;   // 100000
    int ne  = in_sizes[1] / DIM;   // 50000
    int nb  = ne + nu;             // 150000 buckets
    int npart = (nb + PART_BUCKETS - 1) / PART_BUCKETS;   // 1172
    int nbk_pad = npart * PART_BUCKETS;   // 150016

    float* out = (float*)d_out;

    // ws (ints): pcnt[npart] | poffs[npart+1] | pcursor[npart] | offs[nbk_pad]
    //          | ends[nbk_pad] | ovfcnt[1] | ovflist[npart] | pad | payload[2*nnz]*8B
    size_t n_ints = (size_t)npart * 3 + 1 + (size_t)nbk_pad * 2 + 1 + npart;
    size_t pay_off_ints = (n_ints + 1) & ~(size_t)1;
    size_t need = pay_off_ints * 4 + (size_t)2 * nnz * 8;

    if (ws_size < need || npart > NPART_MAX || nu > 131072 || ne > 131072) {
        float* entity_agg = out;
        float* user_agg   = out + (size_t)ne * DIM;
        hipMemsetAsync(d_out, 0, (size_t)out_size * sizeof(float), stream);
        long long total = (long long)nnz * DIM;
        int block = 256;
        long long grid = (total + block - 1) / block;
        coo_scatter_kernel<<<(int)grid, block, 0, stream>>>(
            user_emb, entity_emb, rows, cols, vals, entity_agg, user_agg, nnz);
        return;
    }

    int*   pcnt    = (int*)d_ws;
    int*   poffs   = pcnt + npart;           // npart+1
    int*   pcursor = poffs + npart + 1;
    int*   offs    = pcursor + npart;        // nbk_pad
    int*   ends    = offs + nbk_pad;         // nbk_pad
    int*   ovfcnt  = ends + nbk_pad;         // 1
    int*   ovflist = ovfcnt + 1;             // npart
    uint2* payload = (uint2*)((int*)d_ws + pay_off_ints);

    hipMemsetAsync(pcnt, 0, (size_t)npart * sizeof(int), stream);

    pass0_hist<<<512, 256, 0, stream>>>(rows, cols, pcnt, ne, nnz, npart);
    scan_parts<<<1, 256, 0, stream>>>(pcnt, poffs, pcursor, ovfcnt, npart);
    int g1 = (nnz + EPB - 1) / EPB;
    pass1_part<<<g1, 256, 0, stream>>>(rows, cols, vals, pcursor, payload, ne, nnz, npart);
    pass2_sort<<<npart, 256, 0, stream>>>(payload, poffs, offs, ends, ovfcnt, ovflist);
    int gAgg = (nb + 3) / 4;   // one wave per bucket, 4 waves/block
    agg_buckets<<<gAgg, 256, 0, stream>>>(user_emb, entity_emb, offs, ends, payload, out, nb);
    pass3_ovf<<<64, 256, 0, stream>>>(payload, poffs, ovfcnt, ovflist, user_emb, entity_emb, out);
}

// Round 11
// 235.683 us; speedup vs baseline: 37.4715x; 1.0201x over previous
//
#include <hip/hip_runtime.h>

#define DIM 64
#define PBITS 7
#define PART_BUCKETS 128      // buckets per partition
#define NPART_MAX 1184        // >= ceil(150016/128)=1172
#define EPT 32                // edges per thread, pass1
#define EPB (EPT * 256)       // 8192 edges per block, pass1
#define CAP2 8192             // max records per partition for in-place sort

// ---------------- fallback (round-1) atomic kernel ----------------
__global__ void coo_scatter_kernel(const float* __restrict__ user_emb,
                                   const float* __restrict__ entity_emb,
                                   const int* __restrict__ rows,
                                   const int* __restrict__ cols,
                                   const float* __restrict__ vals,
                                   float* __restrict__ entity_agg,
                                   float* __restrict__ user_agg,
                                   int nnz) {
    long long tid = (long long)blockIdx.x * blockDim.x + threadIdx.x;
    long long total = (long long)nnz * DIM;
    if (tid >= total) return;
    int edge = (int)(tid >> 6);
    int d = (int)(tid & 63);
    int r = rows[edge];
    int c = cols[edge];
    float v = vals[edge];
    atomicAdd(&entity_agg[c * DIM + d], v * user_emb[r * DIM + d]);
    atomicAdd(&user_agg[r * DIM + d], v * entity_emb[c * DIM + d]);
}

// record: uint2 { meta, valbits }; meta = (local7<<18) | (side<<17) | src
// bucket = partition*128 + local7. side 0: gather user_emb; side 1: entity_emb.

// pass0: per-partition histogram (LDS-staged)
__global__ __launch_bounds__(256) void pass0_hist(const int* __restrict__ rows,
                                                  const int* __restrict__ cols,
                                                  int* __restrict__ pcnt,
                                                  int ne, int nnz, int npart) {
    __shared__ int h[NPART_MAX];
    for (int t = threadIdx.x; t < npart; t += 256) h[t] = 0;
    __syncthreads();
    for (int i = blockIdx.x * blockDim.x + threadIdx.x; i < nnz;
         i += gridDim.x * blockDim.x) {
        int c = cols[i];
        int r = rows[i];
        atomicAdd(&h[c >> PBITS], 1);
        atomicAdd(&h[(ne + r) >> PBITS], 1);
    }
    __syncthreads();
    for (int t = threadIdx.x; t < npart; t += 256)
        if (h[t]) atomicAdd(&pcnt[t], h[t]);
}

// scan over npart partition counts (single block, parallel)
__global__ __launch_bounds__(256) void scan_parts(const int* __restrict__ pcnt,
                                                  int* __restrict__ poffs,
                                                  int* __restrict__ pcursor,
                                                  int* __restrict__ ovfcnt,
                                                  int npart) {
    __shared__ int sh[256];
    int t = threadIdx.x;
    int local[8];
    int s = 0;
#pragma unroll
    for (int j = 0; j < 8; ++j) {
        int idx = t * 8 + j;
        local[j] = (idx < npart) ? pcnt[idx] : 0;
        s += local[j];
    }
    sh[t] = s;
    for (int off = 1; off < 256; off <<= 1) {
        __syncthreads();
        int tmp = (t >= off) ? sh[t - off] : 0;
        __syncthreads();
        sh[t] += tmp;
    }
    __syncthreads();
    int run = sh[t] - s;   // exclusive prefix
#pragma unroll
    for (int j = 0; j < 8; ++j) {
        int idx = t * 8 + j;
        if (idx < npart) {
            poffs[idx] = run;
            pcursor[idx] = run;
            run += local[j];
        }
    }
    if (t == 255) poffs[npart] = sh[255];
    if (t == 0) *ovfcnt = 0;
}

// pass1: two sweeps over this block's edges. Sweep A: LDS histogram.
// Claim one contiguous global chunk per (block, partition). Sweep B:
// rebuild record on the fly (L2-hot re-read) and store at rank.
// All writers of a chunk are one block -> single-L2 full-line writes.
__global__ __launch_bounds__(256) void pass1_part(const int* __restrict__ rows,
                                                  const int* __restrict__ cols,
                                                  const float* __restrict__ vals,
                                                  int* __restrict__ pcursor,
                                                  uint2* __restrict__ payload,
                                                  int ne, int nnz, int npart) {
    __shared__ int hist[NPART_MAX];
    __shared__ int cur[NPART_MAX];
    __shared__ int gbase[NPART_MAX];
    for (int t = threadIdx.x; t < npart; t += 256) { hist[t] = 0; cur[t] = 0; }
    __syncthreads();

    int base = blockIdx.x * EPB;
#pragma unroll 4
    for (int k = 0; k < EPT; ++k) {
        int i = base + threadIdx.x + k * 256;
        if (i < nnz) {
            atomicAdd(&hist[cols[i] >> PBITS], 1);
            atomicAdd(&hist[(ne + rows[i]) >> PBITS], 1);
        }
    }
    __syncthreads();
    for (int p = threadIdx.x; p < npart; p += 256) {
        int c_ = hist[p];
        if (c_) gbase[p] = atomicAdd(&pcursor[p], c_);
    }
    __syncthreads();
#pragma unroll 4
    for (int k = 0; k < EPT; ++k) {
        int i = base + threadIdx.x + k * 256;
        if (i < nnz) {
            int r = rows[i];
            int c = cols[i];
            unsigned vb = __float_as_uint(vals[i]);
            int b2 = ne + r;
            int p1 = c >> PBITS;
            int p2 = b2 >> PBITS;
            int rank1 = atomicAdd(&cur[p1], 1);
            payload[(size_t)gbase[p1] + rank1] =
                make_uint2(((unsigned)(c & (PART_BUCKETS - 1)) << 18) | (unsigned)r, vb);
            int rank2 = atomicAdd(&cur[p2], 1);
            payload[(size_t)gbase[p2] + rank2] =
                make_uint2(((unsigned)(b2 & (PART_BUCKETS - 1)) << 18) | (1u << 17) | (unsigned)c, vb);
        }
    }
}

// pass2: one block per partition; in-place counting sort into ALL 128
// buckets; write per-bucket [offs, ends). Select-free agg follows.
__global__ __launch_bounds__(256) void pass2_sort(uint2* __restrict__ payload,
                                                  const int* __restrict__ poffs,
                                                  int* __restrict__ offs,
                                                  int* __restrict__ ends,
                                                  int* __restrict__ ovfcnt,
                                                  int* __restrict__ ovflist) {
    __shared__ int h[PART_BUCKETS], sc[PART_BUCKETS], cu[PART_BUCKETS];
    int p = blockIdx.x;
    int beg = poffs[p];
    int n = poffs[p + 1] - beg;
    int t = threadIdx.x;
    if (t < PART_BUCKETS) h[t] = 0;
    __syncthreads();

    if (n > CAP2) {   // ~43 sigma; handled by pass3 direct atomics
        if (t == 0) {
            int o = atomicAdd(ovfcnt, 1);
            ovflist[o] = p;
        }
        if (t < PART_BUCKETS) {
            offs[p * PART_BUCKETS + t] = beg;
            ends[p * PART_BUCKETS + t] = beg;
        }
        return;
    }

    uint2 rec[32];
#pragma unroll
    for (int k = 0; k < 32; ++k) {
        int idx = t + k * 256;
        if (idx < n) {
            rec[k] = payload[(size_t)beg + idx];
            atomicAdd(&h[(rec[k].x >> 18) & (PART_BUCKETS - 1)], 1);
        }
    }
    __syncthreads();
    if (t == 0) {
        int run = 0;
#pragma unroll
        for (int j = 0; j < PART_BUCKETS; ++j) { sc[j] = run; run += h[j]; }
    }
    __syncthreads();
    if (t < PART_BUCKETS) {
        offs[p * PART_BUCKETS + t] = beg + sc[t];
        ends[p * PART_BUCKETS + t] = beg + sc[t] + h[t];
        cu[t] = sc[t];
    }
    __syncthreads();   // all reads done (records in regs) -> in-place write safe
#pragma unroll
    for (int k = 0; k < 32; ++k) {
        int idx = t + k * 256;
        if (idx < n) {
            int bucket = (rec[k].x >> 18) & (PART_BUCKETS - 1);
            int rank = atomicAdd(&cu[bucket], 1);
            payload[(size_t)beg + rank] = rec[k];
        }
    }
}

// agg: one WAVE per bucket; 4x16-lane groups, 4 records each per main iter
// (16 records / 16 float4-loads in flight). shfl_xor folds groups at end.
__global__ __launch_bounds__(256) void agg_buckets(const float* __restrict__ user_emb,
                                                   const float* __restrict__ entity_emb,
                                                   const int* __restrict__ offs,
                                                   const int* __restrict__ ends,
                                                   const uint2* __restrict__ payload,
                                                   float* __restrict__ out,
                                                   int nbuckets) {
    int bucket = blockIdx.x * 4 + (threadIdx.x >> 6);
    int lane = threadIdx.x & 63;
    if (bucket >= nbuckets) return;
    int beg = offs[bucket];
    int end = ends[bucket];

    int grp = lane >> 4;      // which record of the quad
    int sub = lane & 15;      // float4 slot within the row

    float ax0 = 0.f, ay0 = 0.f, az0 = 0.f, aw0 = 0.f;
    float ax1 = 0.f, ay1 = 0.f, az1 = 0.f, aw1 = 0.f;
    float ax2 = 0.f, ay2 = 0.f, az2 = 0.f, aw2 = 0.f;
    float ax3 = 0.f, ay3 = 0.f, az3 = 0.f, aw3 = 0.f;

    int i = beg;
    for (; i + 16 <= end; i += 16) {
        uint2 r0 = payload[i + grp];
        uint2 r1 = payload[i + 4 + grp];
        uint2 r2 = payload[i + 8 + grp];
        uint2 r3 = payload[i + 12 + grp];
        const float* __restrict__ t0 = (r0.x & (1u << 17)) ? entity_emb : user_emb;
        const float* __restrict__ t1 = (r1.x & (1u << 17)) ? entity_emb : user_emb;
        const float* __restrict__ t2 = (r2.x & (1u << 17)) ? entity_emb : user_emb;
        const float* __restrict__ t3 = (r3.x & (1u << 17)) ? entity_emb : user_emb;
        const float4 e0 = *(const float4*)(t0 + (size_t)(r0.x & 0x1FFFFu) * DIM + sub * 4);
        const float4 e1 = *(const float4*)(t1 + (size_t)(r1.x & 0x1FFFFu) * DIM + sub * 4);
        const float4 e2 = *(const float4*)(t2 + (size_t)(r2.x & 0x1FFFFu) * DIM + sub * 4);
        const float4 e3 = *(const float4*)(t3 + (size_t)(r3.x & 0x1FFFFu) * DIM + sub * 4);
        float v0 = __uint_as_float(r0.y);
        float v1 = __uint_as_float(r1.y);
        float v2 = __uint_as_float(r2.y);
        float v3 = __uint_as_float(r3.y);
        ax0 += v0 * e0.x; ay0 += v0 * e0.y; az0 += v0 * e0.z; aw0 += v0 * e0.w;
        ax1 += v1 * e1.x; ay1 += v1 * e1.y; az1 += v1 * e1.z; aw1 += v1 * e1.w;
        ax2 += v2 * e2.x; ay2 += v2 * e2.y; az2 += v2 * e2.z; aw2 += v2 * e2.w;
        ax3 += v3 * e3.x; ay3 += v3 * e3.y; az3 += v3 * e3.z; aw3 += v3 * e3.w;
    }
    for (; i + 8 <= end; i += 8) {
        uint2 rA = payload[i + grp];
        uint2 rB = payload[i + 4 + grp];
        const float* __restrict__ tA = (rA.x & (1u << 17)) ? entity_emb : user_emb;
        const float* __restrict__ tB = (rB.x & (1u << 17)) ? entity_emb : user_emb;
        const float4 eA = *(const float4*)(tA + (size_t)(rA.x & 0x1FFFFu) * DIM + sub * 4);
        const float4 eB = *(const float4*)(tB + (size_t)(rB.x & 0x1FFFFu) * DIM + sub * 4);
        float vA = __uint_as_float(rA.y);
        float vB = __uint_as_float(rB.y);
        ax0 += vA * eA.x; ay0 += vA * eA.y; az0 += vA * eA.z; aw0 += vA * eA.w;
        ax1 += vB * eB.x; ay1 += vB * eB.y; az1 += vB * eB.z; aw1 += vB * eB.w;
    }
    for (; i < end; i += 4) {
        int j = i + grp;
        bool valid = j < end;
        uint2 r = payload[valid ? j : end - 1];
        const float* __restrict__ t = (r.x & (1u << 17)) ? entity_emb : user_emb;
        const float4 e = *(const float4*)(t + (size_t)(r.x & 0x1FFFFu) * DIM + sub * 4);
        float v = valid ? __uint_as_float(r.y) : 0.f;
        ax0 += v * e.x; ay0 += v * e.y; az0 += v * e.z; aw0 += v * e.w;
    }

    ax0 += ax1 + ax2 + ax3; ay0 += ay1 + ay2 + ay3;
    az0 += az1 + az2 + az3; aw0 += aw1 + aw2 + aw3;
    // fold the 4 lane-groups: lanes l, l^16, l^32, l^48 hold the same dims
    ax0 += __shfl_xor(ax0, 16, 64); ay0 += __shfl_xor(ay0, 16, 64);
    az0 += __shfl_xor(az0, 16, 64); aw0 += __shfl_xor(aw0, 16, 64);
    ax0 += __shfl_xor(ax0, 32, 64); ay0 += __shfl_xor(ay0, 32, 64);
    az0 += __shfl_xor(az0, 32, 64); aw0 += __shfl_xor(aw0, 32, 64);

    if (grp == 0) {
        float4 res = make_float4(ax0, ay0, az0, aw0);
        *(float4*)(out + (size_t)bucket * DIM + sub * 4) = res;
    }
}

// pass3: direct atomics for overflow partitions (normally zero work)
__global__ void pass3_ovf(const uint2* __restrict__ payload,
                          const int* __restrict__ poffs,
                          const int* __restrict__ ovfcnt,
                          const int* __restrict__ ovflist,
                          const float* __restrict__ user_emb,
                          const float* __restrict__ entity_emb,
                          float* __restrict__ out) {
    int no = *ovfcnt;
    for (int o = 0; o < no; ++o) {
        int p = ovflist[o];
        int beg = poffs[p];
        int n = poffs[p + 1] - beg;
        for (int j = blockIdx.x * blockDim.x + threadIdx.x; j < n * 16;
             j += gridDim.x * blockDim.x) {
            uint2 rec = payload[(size_t)beg + (j >> 4)];
            int d4 = (j & 15) * 4;
            const float* tab = (rec.x & (1u << 17)) ? entity_emb : user_emb;
            float v = __uint_as_float(rec.y);
            int bucket = (p << PBITS) | (int)((rec.x >> 18) & (PART_BUCKETS - 1));
            const float* src = tab + (size_t)(rec.x & 0x1FFFFu) * DIM + d4;
            float* dst = out + (size_t)bucket * DIM + d4;
            for (int d = 0; d < 4; ++d) atomicAdd(&dst[d], v * src[d]);
        }
    }
}

extern "C" void kernel_launch(void* const* d_in, const int* in_sizes, int n_in,
                              void* d_out, int out_size, void* d_ws, size_t ws_size,
                              hipStream_t stream) {
    const float* user_emb   = (const float*)d_in[0];  // [n_users, 64]
    const float* entity_emb = (const float*)d_in[1];  // [n_entities, 64]
    const int*   rows       = (const int*)d_in[2];
    const int*   cols       = (const int*)d_in[3];
    const float* vals       = (const float*)d_in[4];
    int nnz = in_sizes[2];
    int nu  = in_sizes[0] / DIM;   // 100000
    int ne  = in_sizes[1] / DIM;   // 50000
    int nb  = ne + nu;             // 150000 buckets
    int npart = (nb + PART_BUCKETS - 1) / PART_BUCKETS;   // 1172
    int nbk_pad = npart * PART_BUCKETS;   // 150016

    float* out = (float*)d_out;

    // ws (ints): pcnt[npart] | poffs[npart+1] | pcursor[npart] | offs[nbk_pad]
    //          | ends[nbk_pad] | ovfcnt[1] | ovflist[npart] | pad | payload[2*nnz]*8B
    size_t n_ints = (size_t)npart * 3 + 1 + (size_t)nbk_pad * 2 + 1 + npart;
    size_t pay_off_ints = (n_ints + 1) & ~(size_t)1;
    size_t need = pay_off_ints * 4 + (size_t)2 * nnz * 8;

    if (ws_size < need || npart > NPART_MAX || nu > 131072 || ne > 131072) {
        float* entity_agg = out;
        float* user_agg   = out + (size_t)ne * DIM;
        hipMemsetAsync(d_out, 0, (size_t)out_size * sizeof(float), stream);
        long long total = (long long)nnz * DIM;
        int block = 256;
        long long grid = (total + block - 1) / block;
        coo_scatter_kernel<<<(int)grid, block, 0, stream>>>(
            user_emb, entity_emb, rows, cols, vals, entity_agg, user_agg, nnz);
        return;
    }

    int*   pcnt    = (int*)d_ws;
    int*   poffs   = pcnt + npart;           // npart+1
    int*   pcursor = poffs + npart + 1;
    int*   offs    = pcursor + npart;        // nbk_pad
    int*   ends    = offs + nbk_pad;         // nbk_pad
    int*   ovfcnt  = ends + nbk_pad;         // 1
    int*   ovflist = ovfcnt + 1;             // npart
    uint2* payload = (uint2*)((int*)d_ws + pay_off_ints);

    hipMemsetAsync(pcnt, 0, (size_t)npart * sizeof(int), stream);

    pass0_hist<<<512, 256, 0, stream>>>(rows, cols, pcnt, ne, nnz, npart);
    scan_parts<<<1, 256, 0, stream>>>(pcnt, poffs, pcursor, ovfcnt, npart);
    int g1 = (nnz + EPB - 1) / EPB;
    pass1_part<<<g1, 256, 0, stream>>>(rows, cols, vals, pcursor, payload, ne, nnz, npart);
    pass2_sort<<<npart, 256, 0, stream>>>(payload, poffs, offs, ends, ovfcnt, ovflist);
    int gAgg = (nb + 3) / 4;   // one wave per bucket, 4 waves/block
    agg_buckets<<<gAgg, 256, 0, stream>>>(user_emb, entity_emb, offs, ends, payload, out, nb);
    pass3_ovf<<<64, 256, 0, stream>>>(payload, poffs, ovfcnt, ovflist, user_emb, entity_emb, out);
}